// Round 3
// baseline (209.870 us; speedup 1.0000x reference)
//
#include <hip/hip_runtime.h>
#include <math.h>

#define BATCH 8192
#define BLK 256        // attention block size (threads = queries per chunk)
#define BLKM 64        // mlp block size
#define NSPLIT 32
#define CHUNK (BATCH / NSPLIT)  // 256 keys per split
#define NQCHUNK (BATCH / BLK)   // 32 query chunks

// ---------------- weight LDS offsets (floats) ----------------
// W_fm:0(128) b_fm:128(16) W_c1:144(256) b_c1:400(16) W_p1:416(192) b_p1:608(12)
// W_c2:620(96) b_c2:716(8) W_p2:724(32) b_p2:756(4) W_c3:760(16) b_c3:776(4)
// rot:780(16) ent:796(16)  total 812

template <int IN, int OUT>
__device__ __forceinline__ void layer_tanh(const float* a, float* out,
                                           const float* __restrict__ W,
                                           const float* __restrict__ bias) {
  float acc[OUT];
#pragma unroll
  for (int o = 0; o < OUT; o++) acc[o] = bias[o];
#pragma unroll
  for (int i = 0; i < IN; i++) {
    float ai = a[i];
#pragma unroll
    for (int o = 0; o < OUT; o++) acc[o] = fmaf(ai, W[i * OUT + o], acc[o]);
  }
#pragma unroll
  for (int o = 0; o < OUT; o++) out[o] = tanhf(acc[o]);
}

// qv[r] = (0.5 * log2(e)) * (x @ rot)  -> inner loop uses exp2f directly.
// kvx[2r] = k = x @ ent, kvx[2r+1] = v = x  (interleaved, 32B per key).
// Also zeroes the epilogue ticket counters for this call.
__global__ __launch_bounds__(BLKM) void mlp_kernel(
    const float* __restrict__ in,
    const float* __restrict__ W_fm, const float* __restrict__ b_fm,
    const float* __restrict__ W_c1, const float* __restrict__ b_c1,
    const float* __restrict__ W_p1, const float* __restrict__ b_p1,
    const float* __restrict__ W_c2, const float* __restrict__ b_c2,
    const float* __restrict__ W_p2, const float* __restrict__ b_p2,
    const float* __restrict__ W_c3, const float* __restrict__ b_c3,
    const float* __restrict__ rot, const float* __restrict__ ent,
    float4* __restrict__ qv, float4* __restrict__ kvx,
    unsigned* __restrict__ tickets) {
  __shared__ float w[812];
  const int t = threadIdx.x;
  // zero the 32 tickets (block 0 only) — re-done every call, graph-safe
  if (blockIdx.x == 0 && t < NQCHUNK) tickets[t] = 0u;
  auto cp = [&](const float* src, int off, int n) {
    for (int i = t; i < n; i += BLKM) w[off + i] = src[i];
  };
  cp(W_fm, 0, 128);  cp(b_fm, 128, 16);
  cp(W_c1, 144, 256); cp(b_c1, 400, 16);
  cp(W_p1, 416, 192); cp(b_p1, 608, 12);
  cp(W_c2, 620, 96);  cp(b_c2, 716, 8);
  cp(W_p2, 724, 32);  cp(b_p2, 756, 4);
  cp(W_c3, 760, 16);  cp(b_c3, 776, 4);
  cp(rot, 780, 16);   cp(ent, 796, 16);
  __syncthreads();

  const int r = blockIdx.x * BLKM + t;
  const float4* in4 = (const float4*)in;
  float4 i0 = in4[r * 2 + 0];
  float4 i1 = in4[r * 2 + 1];
  float a[16], b[16];
  a[0] = i0.x; a[1] = i0.y; a[2] = i0.z; a[3] = i0.w;
  a[4] = i1.x; a[5] = i1.y; a[6] = i1.z; a[7] = i1.w;

  layer_tanh<8, 16>(a, b, w + 0, w + 128);
  layer_tanh<16, 16>(b, a, w + 144, w + 400);
  layer_tanh<16, 12>(a, b, w + 416, w + 608);
  layer_tanh<12, 8>(b, a, w + 620, w + 716);
  layer_tanh<8, 4>(a, b, w + 724, w + 756);
  layer_tanh<4, 4>(b, a, w + 760, w + 776);
  // final x in a[0..3]
  float q[4], k[4];
#pragma unroll
  for (int d = 0; d < 4; d++) {
    q[d] = a[0] * w[780 + 0 * 4 + d] + a[1] * w[780 + 1 * 4 + d] +
           a[2] * w[780 + 2 * 4 + d] + a[3] * w[780 + 3 * 4 + d];
    k[d] = a[0] * w[796 + 0 * 4 + d] + a[1] * w[796 + 1 * 4 + d] +
           a[2] * w[796 + 2 * 4 + d] + a[3] * w[796 + 3 * 4 + d];
  }
  // fold softmax 1/sqrt(4)=0.5 AND log2(e) so exp(s) == exp2(q'.k)
  const float SC = 0.5f * 1.44269504088896340736f;
  qv[r] = make_float4(q[0] * SC, q[1] * SC, q[2] * SC, q[3] * SC);
  kvx[2 * r + 0] = make_float4(k[0], k[1], k[2], k[3]);
  kvx[2 * r + 1] = make_float4(a[0], a[1], a[2], a[3]);
}

__device__ __forceinline__ float dot4(float4 a, float4 b) {
  return fmaf(a.x, b.x, fmaf(a.y, b.y, fmaf(a.z, b.z, a.w * b.w)));
}

// No-max single-pass split attention + fused last-block epilogue.
// |q'.k| <= ~58 << 126, so exp2 cannot overflow f32 and the softmax
// max-rescale cancels exactly in o/l. K/V addresses are wave-uniform.
// grid = (NQCHUNK, NSPLIT). Last block per qchunk (device-scope ticket)
// reduces the 32 partials and applies conv+sigmoid+head.
__global__ __launch_bounds__(BLK) void attn_kernel(
    const float4* __restrict__ kvx, const float4* __restrict__ qv,
    float* __restrict__ l_arr, float4* __restrict__ o_arr,
    unsigned* __restrict__ tickets,
    const float* __restrict__ conv_w, const float* __restrict__ conv_b,
    const float* __restrict__ head_w, const float* __restrict__ head_b,
    float* __restrict__ out) {
  const int t = threadIdx.x;
  const int qi = blockIdx.x * BLK + t;
  const int c0 = blockIdx.y * CHUNK;
  const float4 q = qv[qi];

  float l0 = 0.f, l1 = 0.f;
  float4 o0 = make_float4(0.f, 0.f, 0.f, 0.f);
  float4 o1 = make_float4(0.f, 0.f, 0.f, 0.f);
#pragma unroll 8
  for (int j = 0; j < CHUNK; j += 2) {
    const float4 ka = kvx[(c0 + j) * 2 + 0];
    const float4 va = kvx[(c0 + j) * 2 + 1];
    const float4 kb = kvx[(c0 + j) * 2 + 2];
    const float4 vb = kvx[(c0 + j) * 2 + 3];
    float s0 = dot4(q, ka);
    float s1 = dot4(q, kb);
    float p0 = exp2f(s0);  // raw v_exp_f32 — log2e folded into q
    float p1 = exp2f(s1);
    l0 += p0;
    l1 += p1;
    o0.x = fmaf(p0, va.x, o0.x); o0.y = fmaf(p0, va.y, o0.y);
    o0.z = fmaf(p0, va.z, o0.z); o0.w = fmaf(p0, va.w, o0.w);
    o1.x = fmaf(p1, vb.x, o1.x); o1.y = fmaf(p1, vb.y, o1.y);
    o1.z = fmaf(p1, vb.z, o1.z); o1.w = fmaf(p1, vb.w, o1.w);
  }
  const int idx = blockIdx.y * BATCH + qi;
  l_arr[idx] = l0 + l1;
  o_arr[idx] = make_float4(o0.x + o1.x, o0.y + o1.y, o0.z + o1.z, o0.w + o1.w);

  // ---- fused split-combine: last block per qchunk does the epilogue ----
  __shared__ unsigned tick;
  __threadfence();  // device-scope release of our partials
  if (t == 0) tick = atomicAdd(&tickets[blockIdx.x], 1u);
  __syncthreads();
  if (tick == NSPLIT - 1) {
    __threadfence();  // device-scope acquire — see all blocks' partials
    float l = 0.f;
    float4 o = make_float4(0.f, 0.f, 0.f, 0.f);
#pragma unroll
    for (int s = 0; s < NSPLIT; s++) {
      l += l_arr[s * BATCH + qi];
      float4 os = o_arr[s * BATCH + qi];
      o.x += os.x; o.y += os.y; o.z += os.z; o.w += os.w;
    }
    const float inv = 1.0f / l;
    float z = o.x * inv * conv_w[0] + o.y * inv * conv_w[1] +
              o.z * inv * conv_w[2] + o.w * inv * conv_w[3] + conv_b[0];
    float filtered = 1.0f / (1.0f + __expf(-z));
    float logit = fmaf(filtered, head_w[0], head_b[0]);
    out[qi] = 1.0f / (1.0f + __expf(-logit));
  }
}

extern "C" void kernel_launch(void* const* d_in, const int* in_sizes, int n_in,
                              void* d_out, int out_size, void* d_ws,
                              size_t ws_size, hipStream_t stream) {
  const float* in   = (const float*)d_in[0];
  const float* W_fm = (const float*)d_in[1];
  const float* b_fm = (const float*)d_in[2];
  const float* W_c1 = (const float*)d_in[3];
  const float* b_c1 = (const float*)d_in[4];
  const float* W_p1 = (const float*)d_in[5];
  const float* b_p1 = (const float*)d_in[6];
  const float* W_c2 = (const float*)d_in[7];
  const float* b_c2 = (const float*)d_in[8];
  const float* W_p2 = (const float*)d_in[9];
  const float* b_p2 = (const float*)d_in[10];
  const float* W_c3 = (const float*)d_in[11];
  const float* b_c3 = (const float*)d_in[12];
  const float* rot  = (const float*)d_in[13];
  const float* ent  = (const float*)d_in[14];
  const float* conv_w = (const float*)d_in[15];
  const float* conv_b = (const float*)d_in[16];
  const float* head_w = (const float*)d_in[17];
  const float* head_b = (const float*)d_in[18];
  float* out = (float*)d_out;

  char* ws = (char*)d_ws;
  float4*   qv      = (float4*)(ws + 0);             // 128 KB
  float4*   kvx     = (float4*)(ws + (128 << 10));   // 256 KB
  float*    l_arr   = (float*)(ws + (384 << 10));    // 1 MB
  float4*   o_arr   = (float4*)(ws + (384 << 10) + NSPLIT * BATCH * 4);  // 4 MB
  unsigned* tickets = (unsigned*)(ws + (384 << 10) + NSPLIT * BATCH * 20);

  mlp_kernel<<<BATCH / BLKM, BLKM, 0, stream>>>(
      in, W_fm, b_fm, W_c1, b_c1, W_p1, b_p1, W_c2, b_c2, W_p2, b_p2, W_c3,
      b_c3, rot, ent, qv, kvx, tickets);

  dim3 grid(NQCHUNK, NSPLIT);
  attn_kernel<<<grid, BLK, 0, stream>>>(kvx, qv, l_arr, o_arr, tickets,
                                        conv_w, conv_b, head_w, head_b, out);
}

// Round 4
// 158.370 us; speedup vs baseline: 1.3252x; 1.3252x over previous
//
#include <hip/hip_runtime.h>
#include <math.h>

#define BATCH 8192
#define BLKM 64   // mlp block size
#define BLKA 256  // attention block size: 4 waves, 2 queries/wave, 32 lanes/query

// ---------------- weight LDS offsets (floats) ----------------
// W_fm:0(128) b_fm:128(16) W_c1:144(256) b_c1:400(16) W_p1:416(192) b_p1:608(12)
// W_c2:620(96) b_c2:716(8) W_p2:724(32) b_p2:756(4) W_c3:760(16) b_c3:776(4)
// rot:780(16) ent:796(16)  total 812

template <int IN, int OUT>
__device__ __forceinline__ void layer_tanh(const float* a, float* out,
                                           const float* __restrict__ W,
                                           const float* __restrict__ bias) {
  float acc[OUT];
#pragma unroll
  for (int o = 0; o < OUT; o++) acc[o] = bias[o];
#pragma unroll
  for (int i = 0; i < IN; i++) {
    float ai = a[i];
#pragma unroll
    for (int o = 0; o < OUT; o++) acc[o] = fmaf(ai, W[i * OUT + o], acc[o]);
  }
#pragma unroll
  for (int o = 0; o < OUT; o++) out[o] = tanhf(acc[o]);
}

// qv[r] = (0.5 * log2(e)) * (x @ rot)  -> attention uses exp2f directly.
// kvx[2r] = k = x @ ent, kvx[2r+1] = v = x  (interleaved, 32 B per key).
__global__ __launch_bounds__(BLKM) void mlp_kernel(
    const float* __restrict__ in,
    const float* __restrict__ W_fm, const float* __restrict__ b_fm,
    const float* __restrict__ W_c1, const float* __restrict__ b_c1,
    const float* __restrict__ W_p1, const float* __restrict__ b_p1,
    const float* __restrict__ W_c2, const float* __restrict__ b_c2,
    const float* __restrict__ W_p2, const float* __restrict__ b_p2,
    const float* __restrict__ W_c3, const float* __restrict__ b_c3,
    const float* __restrict__ rot, const float* __restrict__ ent,
    float4* __restrict__ qv, float4* __restrict__ kvx) {
  __shared__ float w[812];
  const int t = threadIdx.x;
  auto cp = [&](const float* src, int off, int n) {
    for (int i = t; i < n; i += BLKM) w[off + i] = src[i];
  };
  cp(W_fm, 0, 128);  cp(b_fm, 128, 16);
  cp(W_c1, 144, 256); cp(b_c1, 400, 16);
  cp(W_p1, 416, 192); cp(b_p1, 608, 12);
  cp(W_c2, 620, 96);  cp(b_c2, 716, 8);
  cp(W_p2, 724, 32);  cp(b_p2, 756, 4);
  cp(W_c3, 760, 16);  cp(b_c3, 776, 4);
  cp(rot, 780, 16);   cp(ent, 796, 16);
  __syncthreads();

  const int r = blockIdx.x * BLKM + t;
  const float4* in4 = (const float4*)in;
  float4 i0 = in4[r * 2 + 0];
  float4 i1 = in4[r * 2 + 1];
  float a[16], b[16];
  a[0] = i0.x; a[1] = i0.y; a[2] = i0.z; a[3] = i0.w;
  a[4] = i1.x; a[5] = i1.y; a[6] = i1.z; a[7] = i1.w;

  layer_tanh<8, 16>(a, b, w + 0, w + 128);
  layer_tanh<16, 16>(b, a, w + 144, w + 400);
  layer_tanh<16, 12>(a, b, w + 416, w + 608);
  layer_tanh<12, 8>(b, a, w + 620, w + 716);
  layer_tanh<8, 4>(a, b, w + 724, w + 756);
  layer_tanh<4, 4>(b, a, w + 760, w + 776);
  // final x in a[0..3]
  float q[4], k[4];
#pragma unroll
  for (int d = 0; d < 4; d++) {
    q[d] = a[0] * w[780 + 0 * 4 + d] + a[1] * w[780 + 1 * 4 + d] +
           a[2] * w[780 + 2 * 4 + d] + a[3] * w[780 + 3 * 4 + d];
    k[d] = a[0] * w[796 + 0 * 4 + d] + a[1] * w[796 + 1 * 4 + d] +
           a[2] * w[796 + 2 * 4 + d] + a[3] * w[796 + 3 * 4 + d];
  }
  // fold softmax 1/sqrt(4)=0.5 AND log2(e) so exp(s) == exp2(q'.k)
  const float SC = 0.5f * 1.44269504088896340736f;
  qv[r] = make_float4(q[0] * SC, q[1] * SC, q[2] * SC, q[3] * SC);
  kvx[2 * r + 0] = make_float4(k[0], k[1], k[2], k[3]);
  kvx[2 * r + 1] = make_float4(a[0], a[1], a[2], a[3]);
}

__device__ __forceinline__ float dot4(float4 a, float4 b) {
  return fmaf(a.x, b.x, fmaf(a.y, b.y, fmaf(a.z, b.z, a.w * b.w)));
}

// Intra-wave split-K attention, fence-free, fused epilogue.
// Wave layout: 2 queries/wave (lane bit 5), 32 key-slices/query (lane bits
// 0-4, INTERLEAVED: key = j*32 + slice) -> at every iteration the wave's
// lanes read 32 consecutive keys = 1 KB contiguous -> fully coalesced
// global_load_dwordx4, no LDS, no scalar-load dep chains, no partials.
// No-max softmax: |q'.k| <= ~58 << 126 so exp2 cannot overflow f32; the
// max-rescale cancels exactly in o/l.
__global__ __launch_bounds__(BLKA) void attn_kernel(
    const float4* __restrict__ kvx, const float4* __restrict__ qv,
    const float* __restrict__ conv_w, const float* __restrict__ conv_b,
    const float* __restrict__ head_w, const float* __restrict__ head_b,
    float* __restrict__ out) {
  const int t = threadIdx.x;
  const int wave = t >> 6;
  const int lane = t & 63;
  const int qsub = lane >> 5;   // which of the wave's 2 queries
  const int slice = lane & 31;  // key slice within the query
  const int qi = blockIdx.x * 8 + wave * 2 + qsub;
  const float4 q = qv[qi];

  float l = 0.f;
  float4 o = make_float4(0.f, 0.f, 0.f, 0.f);
#pragma unroll 4
  for (int j = 0; j < BATCH / 32; j++) {
    const int key = j * 32 + slice;
    const float4 k4 = kvx[2 * key + 0];
    const float4 v4 = kvx[2 * key + 1];
    float s = dot4(q, k4);
    float p = exp2f(s);  // raw v_exp_f32 — log2e folded into q
    l += p;
    o.x = fmaf(p, v4.x, o.x);
    o.y = fmaf(p, v4.y, o.y);
    o.z = fmaf(p, v4.z, o.z);
    o.w = fmaf(p, v4.w, o.w);
  }

  // butterfly reduce over the 32 slice lanes (masks 1..16 never cross bit 5)
#pragma unroll
  for (int m = 16; m >= 1; m >>= 1) {
    l += __shfl_xor(l, m, 64);
    o.x += __shfl_xor(o.x, m, 64);
    o.y += __shfl_xor(o.y, m, 64);
    o.z += __shfl_xor(o.z, m, 64);
    o.w += __shfl_xor(o.w, m, 64);
  }

  if (slice == 0) {
    const float inv = 1.0f / l;
    float z = o.x * inv * conv_w[0] + o.y * inv * conv_w[1] +
              o.z * inv * conv_w[2] + o.w * inv * conv_w[3] + conv_b[0];
    float filtered = 1.0f / (1.0f + __expf(-z));
    float logit = fmaf(filtered, head_w[0], head_b[0]);
    out[qi] = 1.0f / (1.0f + __expf(-logit));
  }
}

extern "C" void kernel_launch(void* const* d_in, const int* in_sizes, int n_in,
                              void* d_out, int out_size, void* d_ws,
                              size_t ws_size, hipStream_t stream) {
  const float* in   = (const float*)d_in[0];
  const float* W_fm = (const float*)d_in[1];
  const float* b_fm = (const float*)d_in[2];
  const float* W_c1 = (const float*)d_in[3];
  const float* b_c1 = (const float*)d_in[4];
  const float* W_p1 = (const float*)d_in[5];
  const float* b_p1 = (const float*)d_in[6];
  const float* W_c2 = (const float*)d_in[7];
  const float* b_c2 = (const float*)d_in[8];
  const float* W_p2 = (const float*)d_in[9];
  const float* b_p2 = (const float*)d_in[10];
  const float* W_c3 = (const float*)d_in[11];
  const float* b_c3 = (const float*)d_in[12];
  const float* rot  = (const float*)d_in[13];
  const float* ent  = (const float*)d_in[14];
  const float* conv_w = (const float*)d_in[15];
  const float* conv_b = (const float*)d_in[16];
  const float* head_w = (const float*)d_in[17];
  const float* head_b = (const float*)d_in[18];
  float* out = (float*)d_out;

  char* ws = (char*)d_ws;
  float4* qv  = (float4*)(ws + 0);            // 128 KB
  float4* kvx = (float4*)(ws + (128 << 10));  // 256 KB (k/v interleaved)

  mlp_kernel<<<BATCH / BLKM, BLKM, 0, stream>>>(
      in, W_fm, b_fm, W_c1, b_c1, W_p1, b_p1, W_c2, b_c2, W_p2, b_p2, W_c3,
      b_c3, rot, ent, qv, kvx);

  attn_kernel<<<BATCH / 8, BLKA, 0, stream>>>(kvx, qv, conv_w, conv_b,
                                              head_w, head_b, out);
}

// Round 5
// 141.293 us; speedup vs baseline: 1.4854x; 1.1209x over previous
//
#include <hip/hip_runtime.h>
#include <math.h>

#define BATCH 8192
#define BLK 256        // attention/combine block size
#define BLKM 64        // mlp block size
#define NSPLIT 64
#define CHUNK (BATCH / NSPLIT)  // 128 keys per split

// ---------------- weight LDS offsets (floats) ----------------
// W_fm:0(128) b_fm:128(16) W_c1:144(256) b_c1:400(16) W_p1:416(192) b_p1:608(12)
// W_c2:620(96) b_c2:716(8) W_p2:724(32) b_p2:756(4) W_c3:760(16) b_c3:776(4)
// rot:780(16) ent:796(16)  total 812

template <int IN, int OUT>
__device__ __forceinline__ void layer_tanh(const float* a, float* out,
                                           const float* __restrict__ W,
                                           const float* __restrict__ bias) {
  float acc[OUT];
#pragma unroll
  for (int o = 0; o < OUT; o++) acc[o] = bias[o];
#pragma unroll
  for (int i = 0; i < IN; i++) {
    float ai = a[i];
#pragma unroll
    for (int o = 0; o < OUT; o++) acc[o] = fmaf(ai, W[i * OUT + o], acc[o]);
  }
#pragma unroll
  for (int o = 0; o < OUT; o++) out[o] = tanhf(acc[o]);
}

// qv[r] = (0.5 * log2(e)) * (x @ rot)  -> attention uses exp2f directly.
// kvx[2r] = k = x @ ent, kvx[2r+1] = v = x  (interleaved, 32 B per key).
__global__ __launch_bounds__(BLKM) void mlp_kernel(
    const float* __restrict__ in,
    const float* __restrict__ W_fm, const float* __restrict__ b_fm,
    const float* __restrict__ W_c1, const float* __restrict__ b_c1,
    const float* __restrict__ W_p1, const float* __restrict__ b_p1,
    const float* __restrict__ W_c2, const float* __restrict__ b_c2,
    const float* __restrict__ W_p2, const float* __restrict__ b_p2,
    const float* __restrict__ W_c3, const float* __restrict__ b_c3,
    const float* __restrict__ rot, const float* __restrict__ ent,
    float4* __restrict__ qv, float4* __restrict__ kvx) {
  __shared__ float w[812];
  const int t = threadIdx.x;
  auto cp = [&](const float* src, int off, int n) {
    for (int i = t; i < n; i += BLKM) w[off + i] = src[i];
  };
  cp(W_fm, 0, 128);  cp(b_fm, 128, 16);
  cp(W_c1, 144, 256); cp(b_c1, 400, 16);
  cp(W_p1, 416, 192); cp(b_p1, 608, 12);
  cp(W_c2, 620, 96);  cp(b_c2, 716, 8);
  cp(W_p2, 724, 32);  cp(b_p2, 756, 4);
  cp(W_c3, 760, 16);  cp(b_c3, 776, 4);
  cp(rot, 780, 16);   cp(ent, 796, 16);
  __syncthreads();

  const int r = blockIdx.x * BLKM + t;
  const float4* in4 = (const float4*)in;
  float4 i0 = in4[r * 2 + 0];
  float4 i1 = in4[r * 2 + 1];
  float a[16], b[16];
  a[0] = i0.x; a[1] = i0.y; a[2] = i0.z; a[3] = i0.w;
  a[4] = i1.x; a[5] = i1.y; a[6] = i1.z; a[7] = i1.w;

  layer_tanh<8, 16>(a, b, w + 0, w + 128);
  layer_tanh<16, 16>(b, a, w + 144, w + 400);
  layer_tanh<16, 12>(a, b, w + 416, w + 608);
  layer_tanh<12, 8>(b, a, w + 620, w + 716);
  layer_tanh<8, 4>(a, b, w + 724, w + 756);
  layer_tanh<4, 4>(b, a, w + 760, w + 776);
  // final x in a[0..3]
  float q[4], k[4];
#pragma unroll
  for (int d = 0; d < 4; d++) {
    q[d] = a[0] * w[780 + 0 * 4 + d] + a[1] * w[780 + 1 * 4 + d] +
           a[2] * w[780 + 2 * 4 + d] + a[3] * w[780 + 3 * 4 + d];
    k[d] = a[0] * w[796 + 0 * 4 + d] + a[1] * w[796 + 1 * 4 + d] +
           a[2] * w[796 + 2 * 4 + d] + a[3] * w[796 + 3 * 4 + d];
  }
  // fold softmax 1/sqrt(4)=0.5 AND log2(e) so exp(s) == exp2(q'.k)
  const float SC = 0.5f * 1.44269504088896340736f;
  qv[r] = make_float4(q[0] * SC, q[1] * SC, q[2] * SC, q[3] * SC);
  kvx[2 * r + 0] = make_float4(k[0], k[1], k[2], k[3]);
  kvx[2 * r + 1] = make_float4(a[0], a[1], a[2], a[3]);
}

__device__ __forceinline__ float dot4(float4 a, float4 b) {
  return fmaf(a.x, b.x, fmaf(a.y, b.y, fmaf(a.z, b.z, a.w * b.w)));
}

// Split-K attention partial, wave-uniform K/V loads.
// Each thread owns one query; K/V addresses depend only on blockIdx.y and
// the loop counter -> compiler emits s_load through the scalar cache: ONE
// 32B load serves all 64 lanes (0.5 B per (q,k) visit vs 32 B for per-lane
// loads -- round-4 counters showed the per-lane variant is L2-bound at
// 2.1 GB of cache traffic). No LDS, no fences (round-3 counters showed
// per-block __threadfence thrashes L2: FETCH 10x, VALUBusy 20%).
// No-max softmax: |q'.k| <= ~58 << 126 so exp2 cannot overflow f32; the
// max-rescale cancels exactly in o/l. NSPLIT=64 -> 2048 blocks, 8
// waves/SIMD to hide scalar-load latency (round-2 NSPLIT=32 sat at
// occupancy ~30%, ~3.5x above the 8.5us VALU floor).
__global__ __launch_bounds__(BLK) void attn_partial(
    const float4* __restrict__ kvx, const float4* __restrict__ qv,
    float* __restrict__ l_arr, float4* __restrict__ o_arr) {
  const int t = threadIdx.x;
  const int qi = blockIdx.x * BLK + t;
  const int c0 = blockIdx.y * CHUNK;
  const float4 q = qv[qi];

  float l0 = 0.f, l1 = 0.f;
  float4 o0 = make_float4(0.f, 0.f, 0.f, 0.f);
  float4 o1 = make_float4(0.f, 0.f, 0.f, 0.f);
#pragma unroll 4
  for (int j = 0; j < CHUNK; j += 2) {
    const float4 ka = kvx[(c0 + j) * 2 + 0];
    const float4 va = kvx[(c0 + j) * 2 + 1];
    const float4 kb = kvx[(c0 + j) * 2 + 2];
    const float4 vb = kvx[(c0 + j) * 2 + 3];
    float s0 = dot4(q, ka);
    float s1 = dot4(q, kb);
    float p0 = exp2f(s0);  // raw v_exp_f32 — log2e folded into q
    float p1 = exp2f(s1);
    l0 += p0;
    l1 += p1;
    o0.x = fmaf(p0, va.x, o0.x); o0.y = fmaf(p0, va.y, o0.y);
    o0.z = fmaf(p0, va.z, o0.z); o0.w = fmaf(p0, va.w, o0.w);
    o1.x = fmaf(p1, vb.x, o1.x); o1.y = fmaf(p1, vb.y, o1.y);
    o1.z = fmaf(p1, vb.z, o1.z); o1.w = fmaf(p1, vb.w, o1.w);
  }
  const int idx = blockIdx.y * BATCH + qi;
  l_arr[idx] = l0 + l1;
  o_arr[idx] = make_float4(o0.x + o1.x, o0.y + o1.y, o0.z + o1.z, o0.w + o1.w);
}

__global__ __launch_bounds__(BLK) void combine_kernel(
    const float* __restrict__ l_arr, const float4* __restrict__ o_arr,
    const float* __restrict__ conv_w, const float* __restrict__ conv_b,
    const float* __restrict__ head_w, const float* __restrict__ head_b,
    float* __restrict__ out) {
  const int qi = blockIdx.x * BLK + threadIdx.x;
  float l = 0.f;
  float4 o = make_float4(0.f, 0.f, 0.f, 0.f);
#pragma unroll
  for (int s = 0; s < NSPLIT; s++) {
    l += l_arr[s * BATCH + qi];
    float4 os = o_arr[s * BATCH + qi];
    o.x += os.x; o.y += os.y; o.z += os.z; o.w += os.w;
  }
  const float inv = 1.0f / l;
  float z = o.x * inv * conv_w[0] + o.y * inv * conv_w[1] +
            o.z * inv * conv_w[2] + o.w * inv * conv_w[3] + conv_b[0];
  float filtered = 1.0f / (1.0f + __expf(-z));
  float logit = fmaf(filtered, head_w[0], head_b[0]);
  out[qi] = 1.0f / (1.0f + __expf(-logit));
}

extern "C" void kernel_launch(void* const* d_in, const int* in_sizes, int n_in,
                              void* d_out, int out_size, void* d_ws,
                              size_t ws_size, hipStream_t stream) {
  const float* in   = (const float*)d_in[0];
  const float* W_fm = (const float*)d_in[1];
  const float* b_fm = (const float*)d_in[2];
  const float* W_c1 = (const float*)d_in[3];
  const float* b_c1 = (const float*)d_in[4];
  const float* W_p1 = (const float*)d_in[5];
  const float* b_p1 = (const float*)d_in[6];
  const float* W_c2 = (const float*)d_in[7];
  const float* b_c2 = (const float*)d_in[8];
  const float* W_p2 = (const float*)d_in[9];
  const float* b_p2 = (const float*)d_in[10];
  const float* W_c3 = (const float*)d_in[11];
  const float* b_c3 = (const float*)d_in[12];
  const float* rot  = (const float*)d_in[13];
  const float* ent  = (const float*)d_in[14];
  const float* conv_w = (const float*)d_in[15];
  const float* conv_b = (const float*)d_in[16];
  const float* head_w = (const float*)d_in[17];
  const float* head_b = (const float*)d_in[18];
  float* out = (float*)d_out;

  char* ws = (char*)d_ws;
  float4* qv  = (float4*)(ws + 0);            // 128 KB
  float4* kvx = (float4*)(ws + (128 << 10));  // 256 KB (k/v interleaved)
  float*  l_arr = (float*)(ws + (384 << 10));                          // 2 MB
  float4* o_arr = (float4*)(ws + (384 << 10) + NSPLIT * BATCH * 4);    // 8 MB

  mlp_kernel<<<BATCH / BLKM, BLKM, 0, stream>>>(
      in, W_fm, b_fm, W_c1, b_c1, W_p1, b_p1, W_c2, b_c2, W_p2, b_p2, W_c3,
      b_c3, rot, ent, qv, kvx);

  dim3 grid(BATCH / BLK, NSPLIT);
  attn_partial<<<grid, BLK, 0, stream>>>(kvx, qv, l_arr, o_arr);

  combine_kernel<<<BATCH / BLK, BLK, 0, stream>>>(
      l_arr, o_arr, conv_w, conv_b, head_w, head_b, out);
}

// Round 6
// 138.969 us; speedup vs baseline: 1.5102x; 1.0167x over previous
//
#include <hip/hip_runtime.h>
#include <math.h>

#define BATCH 8192
#define BLK 256        // attention block size
#define BLKM 64        // mlp block size
#define BLKC 64        // combine block size (128 blocks -> 4x CU coverage)
#define NSPLIT 32      // round-2-proven best split count
#define CHUNK (BATCH / NSPLIT)  // 256 keys per split

// ---------------- weight LDS offsets (floats) ----------------
// W_fm:0(128) b_fm:128(16) W_c1:144(256) b_c1:400(16) W_p1:416(192) b_p1:608(12)
// W_c2:620(96) b_c2:716(8) W_p2:724(32) b_p2:756(4) W_c3:760(16) b_c3:776(4)
// rot:780(16) ent:796(16)  total 812

template <int IN, int OUT>
__device__ __forceinline__ void layer_tanh(const float* a, float* out,
                                           const float* __restrict__ W,
                                           const float* __restrict__ bias) {
  float acc[OUT];
#pragma unroll
  for (int o = 0; o < OUT; o++) acc[o] = bias[o];
#pragma unroll
  for (int i = 0; i < IN; i++) {
    float ai = a[i];
#pragma unroll
    for (int o = 0; o < OUT; o++) acc[o] = fmaf(ai, W[i * OUT + o], acc[o]);
  }
#pragma unroll
  for (int o = 0; o < OUT; o++) out[o] = tanhf(acc[o]);
}

// qv[r] = (0.5 * log2(e)) * (x @ rot)  -> attention uses exp2f directly.
// kvx[2r] = k = x @ ent, kvx[2r+1] = v = x  (interleaved, 32 B per key).
__global__ __launch_bounds__(BLKM) void mlp_kernel(
    const float* __restrict__ in,
    const float* __restrict__ W_fm, const float* __restrict__ b_fm,
    const float* __restrict__ W_c1, const float* __restrict__ b_c1,
    const float* __restrict__ W_p1, const float* __restrict__ b_p1,
    const float* __restrict__ W_c2, const float* __restrict__ b_c2,
    const float* __restrict__ W_p2, const float* __restrict__ b_p2,
    const float* __restrict__ W_c3, const float* __restrict__ b_c3,
    const float* __restrict__ rot, const float* __restrict__ ent,
    float4* __restrict__ qv, float4* __restrict__ kvx) {
  __shared__ float w[812];
  const int t = threadIdx.x;
  auto cp = [&](const float* src, int off, int n) {
    for (int i = t; i < n; i += BLKM) w[off + i] = src[i];
  };
  cp(W_fm, 0, 128);  cp(b_fm, 128, 16);
  cp(W_c1, 144, 256); cp(b_c1, 400, 16);
  cp(W_p1, 416, 192); cp(b_p1, 608, 12);
  cp(W_c2, 620, 96);  cp(b_c2, 716, 8);
  cp(W_p2, 724, 32);  cp(b_p2, 756, 4);
  cp(W_c3, 760, 16);  cp(b_c3, 776, 4);
  cp(rot, 780, 16);   cp(ent, 796, 16);
  __syncthreads();

  const int r = blockIdx.x * BLKM + t;
  const float4* in4 = (const float4*)in;
  float4 i0 = in4[r * 2 + 0];
  float4 i1 = in4[r * 2 + 1];
  float a[16], b[16];
  a[0] = i0.x; a[1] = i0.y; a[2] = i0.z; a[3] = i0.w;
  a[4] = i1.x; a[5] = i1.y; a[6] = i1.z; a[7] = i1.w;

  layer_tanh<8, 16>(a, b, w + 0, w + 128);
  layer_tanh<16, 16>(b, a, w + 144, w + 400);
  layer_tanh<16, 12>(a, b, w + 416, w + 608);
  layer_tanh<12, 8>(b, a, w + 620, w + 716);
  layer_tanh<8, 4>(a, b, w + 724, w + 756);
  layer_tanh<4, 4>(b, a, w + 760, w + 776);
  // final x in a[0..3]
  float q[4], k[4];
#pragma unroll
  for (int d = 0; d < 4; d++) {
    q[d] = a[0] * w[780 + 0 * 4 + d] + a[1] * w[780 + 1 * 4 + d] +
           a[2] * w[780 + 2 * 4 + d] + a[3] * w[780 + 3 * 4 + d];
    k[d] = a[0] * w[796 + 0 * 4 + d] + a[1] * w[796 + 1 * 4 + d] +
           a[2] * w[796 + 2 * 4 + d] + a[3] * w[796 + 3 * 4 + d];
  }
  // fold softmax 1/sqrt(4)=0.5 AND log2(e) so exp(s) == exp2(q'.k)
  const float SC = 0.5f * 1.44269504088896340736f;
  qv[r] = make_float4(q[0] * SC, q[1] * SC, q[2] * SC, q[3] * SC);
  kvx[2 * r + 0] = make_float4(k[0], k[1], k[2], k[3]);
  kvx[2 * r + 1] = make_float4(a[0], a[1], a[2], a[3]);
}

__device__ __forceinline__ float dot4(float4 a, float4 b) {
  return fmaf(a.x, b.x, fmaf(a.y, b.y, fmaf(a.z, b.z, a.w * b.w)));
}

// Split-K attention partial, wave-uniform K/V loads through the scalar
// cache: ONE 32B s_load serves all 64 lanes (0.5 B per (q,k) visit; the
// per-lane-coalesced variant measured L2-bound at 2.1 GB — round 4).
// No LDS, no fences (round 3: per-block __threadfence thrashes L2).
// No-max softmax: |q'.k| <= ~58 << 126 so exp2 cannot overflow f32; the
// max-rescale cancels exactly in o/l. NSPLIT=32 is the measured best
// (round 2: 130.7us total vs round 5's NSPLIT=64 at 141.3us — extra
// splits double partial traffic for no attn gain). unroll 8 keeps ~4
// wide s_load batches in flight per wave.
__global__ __launch_bounds__(BLK) void attn_partial(
    const float4* __restrict__ kvx, const float4* __restrict__ qv,
    float* __restrict__ l_arr, float4* __restrict__ o_arr) {
  const int t = threadIdx.x;
  const int qi = blockIdx.x * BLK + t;
  const int c0 = blockIdx.y * CHUNK;
  const float4 q = qv[qi];

  float l0 = 0.f, l1 = 0.f;
  float4 o0 = make_float4(0.f, 0.f, 0.f, 0.f);
  float4 o1 = make_float4(0.f, 0.f, 0.f, 0.f);
#pragma unroll 8
  for (int j = 0; j < CHUNK; j += 2) {
    const float4 ka = kvx[(c0 + j) * 2 + 0];
    const float4 va = kvx[(c0 + j) * 2 + 1];
    const float4 kb = kvx[(c0 + j) * 2 + 2];
    const float4 vb = kvx[(c0 + j) * 2 + 3];
    float s0 = dot4(q, ka);
    float s1 = dot4(q, kb);
    float p0 = exp2f(s0);  // raw v_exp_f32 — log2e folded into q
    float p1 = exp2f(s1);
    l0 += p0;
    l1 += p1;
    o0.x = fmaf(p0, va.x, o0.x); o0.y = fmaf(p0, va.y, o0.y);
    o0.z = fmaf(p0, va.z, o0.z); o0.w = fmaf(p0, va.w, o0.w);
    o1.x = fmaf(p1, vb.x, o1.x); o1.y = fmaf(p1, vb.y, o1.y);
    o1.z = fmaf(p1, vb.z, o1.z); o1.w = fmaf(p1, vb.w, o1.w);
  }
  const int idx = blockIdx.y * BATCH + qi;
  l_arr[idx] = l0 + l1;
  o_arr[idx] = make_float4(o0.x + o1.x, o0.y + o1.y, o0.z + o1.z, o0.w + o1.w);
}

// 64-thread blocks -> 128 blocks: spreads the 5 MB partial reduction over
// 4x more CUs than the old 32x256 config.
__global__ __launch_bounds__(BLKC) void combine_kernel(
    const float* __restrict__ l_arr, const float4* __restrict__ o_arr,
    const float* __restrict__ conv_w, const float* __restrict__ conv_b,
    const float* __restrict__ head_w, const float* __restrict__ head_b,
    float* __restrict__ out) {
  const int qi = blockIdx.x * BLKC + threadIdx.x;
  float l = 0.f;
  float4 o = make_float4(0.f, 0.f, 0.f, 0.f);
#pragma unroll
  for (int s = 0; s < NSPLIT; s++) {
    l += l_arr[s * BATCH + qi];
    float4 os = o_arr[s * BATCH + qi];
    o.x += os.x; o.y += os.y; o.z += os.z; o.w += os.w;
  }
  const float inv = 1.0f / l;
  float z = o.x * inv * conv_w[0] + o.y * inv * conv_w[1] +
            o.z * inv * conv_w[2] + o.w * inv * conv_w[3] + conv_b[0];
  float filtered = 1.0f / (1.0f + __expf(-z));
  float logit = fmaf(filtered, head_w[0], head_b[0]);
  out[qi] = 1.0f / (1.0f + __expf(-logit));
}

extern "C" void kernel_launch(void* const* d_in, const int* in_sizes, int n_in,
                              void* d_out, int out_size, void* d_ws,
                              size_t ws_size, hipStream_t stream) {
  const float* in   = (const float*)d_in[0];
  const float* W_fm = (const float*)d_in[1];
  const float* b_fm = (const float*)d_in[2];
  const float* W_c1 = (const float*)d_in[3];
  const float* b_c1 = (const float*)d_in[4];
  const float* W_p1 = (const float*)d_in[5];
  const float* b_p1 = (const float*)d_in[6];
  const float* W_c2 = (const float*)d_in[7];
  const float* b_c2 = (const float*)d_in[8];
  const float* W_p2 = (const float*)d_in[9];
  const float* b_p2 = (const float*)d_in[10];
  const float* W_c3 = (const float*)d_in[11];
  const float* b_c3 = (const float*)d_in[12];
  const float* rot  = (const float*)d_in[13];
  const float* ent  = (const float*)d_in[14];
  const float* conv_w = (const float*)d_in[15];
  const float* conv_b = (const float*)d_in[16];
  const float* head_w = (const float*)d_in[17];
  const float* head_b = (const float*)d_in[18];
  float* out = (float*)d_out;

  char* ws = (char*)d_ws;
  float4* qv  = (float4*)(ws + 0);            // 128 KB
  float4* kvx = (float4*)(ws + (128 << 10));  // 256 KB (k/v interleaved)
  float*  l_arr = (float*)(ws + (384 << 10));                          // 1 MB
  float4* o_arr = (float4*)(ws + (384 << 10) + NSPLIT * BATCH * 4);    // 4 MB

  mlp_kernel<<<BATCH / BLKM, BLKM, 0, stream>>>(
      in, W_fm, b_fm, W_c1, b_c1, W_p1, b_p1, W_c2, b_c2, W_p2, b_p2, W_c3,
      b_c3, rot, ent, qv, kvx);

  dim3 grid(BATCH / BLK, NSPLIT);
  attn_partial<<<grid, BLK, 0, stream>>>(kvx, qv, l_arr, o_arr);

  combine_kernel<<<BATCH / BLKC, BLKC, 0, stream>>>(
      l_arr, o_arr, conv_w, conv_b, head_w, head_b, out);
}

// Round 7
// 131.495 us; speedup vs baseline: 1.5960x; 1.0568x over previous
//
#include <hip/hip_runtime.h>
#include <math.h>

#define BATCH 8192
#define BLK 256        // attention block size
#define BLKM 64        // mlp block size
#define BLKC 64        // combine block size
#define NSPLIT 32      // measured best (r2 vs r5)
#define CHUNK (BATCH / NSPLIT)  // 256 keys per split
#define NQCHUNK (BATCH / BLK)

// ---------------- weight LDS offsets (floats) ----------------
// W_fm:0(128) b_fm:128(16) W_c1:144(256) b_c1:400(16) W_p1:416(192) b_p1:608(12)
// W_c2:620(96) b_c2:716(8) W_p2:724(32) b_p2:756(4) W_c3:760(16) b_c3:776(4)
// rot:780(16) ent:796(16)  total 812

// exact tanh via exp2+rcp: tanh(x) = 1 - 2/(exp2(2*log2e*x)+1).
// v_exp_f32 + v_rcp_f32 are ~1ulp; robust at +-inf ends. ~5 inst vs ~20 for
// libm tanhf.
__device__ __forceinline__ float fast_tanh(float x) {
  float e = __builtin_amdgcn_exp2f(x * 2.885390081777927f);
  return 1.0f - 2.0f * __builtin_amdgcn_rcpf(e + 1.0f);
}

template <int IN, int OUT>
__device__ __forceinline__ void layer_tanh(const float* a, float* out,
                                           const float* __restrict__ W,
                                           const float* __restrict__ bias) {
  float acc[OUT];
#pragma unroll
  for (int o = 0; o < OUT; o++) acc[o] = bias[o];
#pragma unroll
  for (int i = 0; i < IN; i++) {
    float ai = a[i];
#pragma unroll
    for (int o = 0; o < OUT; o++) acc[o] = fmaf(ai, W[i * OUT + o], acc[o]);
  }
#pragma unroll
  for (int o = 0; o < OUT; o++) out[o] = fast_tanh(acc[o]);
}

// qv[r] = (0.5 * log2(e)) * (x @ rot)  -> attention uses exp2 directly.
// kvx[2r] = k = x @ ent, kvx[2r+1] = v = x  (interleaved, 32 B per key).
__global__ __launch_bounds__(BLKM) void mlp_kernel(
    const float* __restrict__ in,
    const float* __restrict__ W_fm, const float* __restrict__ b_fm,
    const float* __restrict__ W_c1, const float* __restrict__ b_c1,
    const float* __restrict__ W_p1, const float* __restrict__ b_p1,
    const float* __restrict__ W_c2, const float* __restrict__ b_c2,
    const float* __restrict__ W_p2, const float* __restrict__ b_p2,
    const float* __restrict__ W_c3, const float* __restrict__ b_c3,
    const float* __restrict__ rot, const float* __restrict__ ent,
    float4* __restrict__ qv, float4* __restrict__ kvx) {
  __shared__ float w[812];
  const int t = threadIdx.x;
  auto cp = [&](const float* src, int off, int n) {
    for (int i = t; i < n; i += BLKM) w[off + i] = src[i];
  };
  cp(W_fm, 0, 128);  cp(b_fm, 128, 16);
  cp(W_c1, 144, 256); cp(b_c1, 400, 16);
  cp(W_p1, 416, 192); cp(b_p1, 608, 12);
  cp(W_c2, 620, 96);  cp(b_c2, 716, 8);
  cp(W_p2, 724, 32);  cp(b_p2, 756, 4);
  cp(W_c3, 760, 16);  cp(b_c3, 776, 4);
  cp(rot, 780, 16);   cp(ent, 796, 16);
  __syncthreads();

  const int r = blockIdx.x * BLKM + t;
  const float4* in4 = (const float4*)in;
  float4 i0 = in4[r * 2 + 0];
  float4 i1 = in4[r * 2 + 1];
  float a[16], b[16];
  a[0] = i0.x; a[1] = i0.y; a[2] = i0.z; a[3] = i0.w;
  a[4] = i1.x; a[5] = i1.y; a[6] = i1.z; a[7] = i1.w;

  layer_tanh<8, 16>(a, b, w + 0, w + 128);
  layer_tanh<16, 16>(b, a, w + 144, w + 400);
  layer_tanh<16, 12>(a, b, w + 416, w + 608);
  layer_tanh<12, 8>(b, a, w + 620, w + 716);
  layer_tanh<8, 4>(a, b, w + 724, w + 756);
  layer_tanh<4, 4>(b, a, w + 760, w + 776);
  // final x in a[0..3]
  float q[4], k[4];
#pragma unroll
  for (int d = 0; d < 4; d++) {
    q[d] = a[0] * w[780 + 0 * 4 + d] + a[1] * w[780 + 1 * 4 + d] +
           a[2] * w[780 + 2 * 4 + d] + a[3] * w[780 + 3 * 4 + d];
    k[d] = a[0] * w[796 + 0 * 4 + d] + a[1] * w[796 + 1 * 4 + d] +
           a[2] * w[796 + 2 * 4 + d] + a[3] * w[796 + 3 * 4 + d];
  }
  // fold softmax 1/sqrt(4)=0.5 AND log2(e) so exp(s) == exp2(q'.k)
  const float SC = 0.5f * 1.44269504088896340736f;
  qv[r] = make_float4(q[0] * SC, q[1] * SC, q[2] * SC, q[3] * SC);
  kvx[2 * r + 0] = make_float4(k[0], k[1], k[2], k[3]);
  kvx[2 * r + 1] = make_float4(a[0], a[1], a[2], a[3]);
}

__device__ __forceinline__ float dot4(float4 a, float4 b) {
  return fmaf(a.x, b.x, fmaf(a.y, b.y, fmaf(a.z, b.z, a.w * b.w)));
}

// Split-K attention partial, wave-uniform K/V loads through the scalar
// cache (ONE 32B s_load serves 64 lanes; per-lane-coalesced variant was
// L2-bound at 2.1 GB — round 4). No LDS, no fences (round 3).
//
// GRID ORDER MATTERS: blockIdx.x = SPLIT, blockIdx.y = QCHUNK. Co-resident
// blocks on a CU are ~gridDim.x*8=256 apart in linear index -> same
// blockIdx.x -> same 8 KB K/V chunk -> scalar working set fits the 16 KB
// K$ (the old (qchunk,split) order put 4 different chunks = 32 KB on each
// CU -> K$ thrash -> every s_load batch at L2 latency).
//
// No-max softmax: |q'.k| <= ~58 << 126 so exp2 cannot overflow f32; the
// max-rescale cancels exactly in o/l.
__global__ __launch_bounds__(BLK) void attn_partial(
    const float4* __restrict__ kvx, const float4* __restrict__ qv,
    float* __restrict__ l_arr, float4* __restrict__ o_arr) {
  const int t = threadIdx.x;
  const int split = blockIdx.x;
  const int qi = blockIdx.y * BLK + t;
  const int c0 = split * CHUNK;
  const float4 q = qv[qi];

  float l0 = 0.f, l1 = 0.f;
  float4 o0 = make_float4(0.f, 0.f, 0.f, 0.f);
  float4 o1 = make_float4(0.f, 0.f, 0.f, 0.f);
#pragma unroll 8
  for (int j = 0; j < CHUNK; j += 2) {
    const float4 ka = kvx[(c0 + j) * 2 + 0];
    const float4 va = kvx[(c0 + j) * 2 + 1];
    const float4 kb = kvx[(c0 + j) * 2 + 2];
    const float4 vb = kvx[(c0 + j) * 2 + 3];
    float s0 = dot4(q, ka);
    float s1 = dot4(q, kb);
    float p0 = __builtin_amdgcn_exp2f(s0);  // raw v_exp_f32
    float p1 = __builtin_amdgcn_exp2f(s1);
    l0 += p0;
    l1 += p1;
    o0.x = fmaf(p0, va.x, o0.x); o0.y = fmaf(p0, va.y, o0.y);
    o0.z = fmaf(p0, va.z, o0.z); o0.w = fmaf(p0, va.w, o0.w);
    o1.x = fmaf(p1, vb.x, o1.x); o1.y = fmaf(p1, vb.y, o1.y);
    o1.z = fmaf(p1, vb.z, o1.z); o1.w = fmaf(p1, vb.w, o1.w);
  }
  const int idx = split * BATCH + qi;
  l_arr[idx] = l0 + l1;
  o_arr[idx] = make_float4(o0.x + o1.x, o0.y + o1.y, o0.z + o1.z, o0.w + o1.w);
}

// 64-thread blocks -> 128 blocks: spreads the 5 MB partial reduction wide.
__global__ __launch_bounds__(BLKC) void combine_kernel(
    const float* __restrict__ l_arr, const float4* __restrict__ o_arr,
    const float* __restrict__ conv_w, const float* __restrict__ conv_b,
    const float* __restrict__ head_w, const float* __restrict__ head_b,
    float* __restrict__ out) {
  const int qi = blockIdx.x * BLKC + threadIdx.x;
  float l = 0.f;
  float4 o = make_float4(0.f, 0.f, 0.f, 0.f);
#pragma unroll
  for (int s = 0; s < NSPLIT; s++) {
    l += l_arr[s * BATCH + qi];
    float4 os = o_arr[s * BATCH + qi];
    o.x += os.x; o.y += os.y; o.z += os.z; o.w += os.w;
  }
  const float inv = 1.0f / l;
  float z = o.x * inv * conv_w[0] + o.y * inv * conv_w[1] +
            o.z * inv * conv_w[2] + o.w * inv * conv_w[3] + conv_b[0];
  float filtered = 1.0f / (1.0f + __expf(-z));
  float logit = fmaf(filtered, head_w[0], head_b[0]);
  out[qi] = 1.0f / (1.0f + __expf(-logit));
}

extern "C" void kernel_launch(void* const* d_in, const int* in_sizes, int n_in,
                              void* d_out, int out_size, void* d_ws,
                              size_t ws_size, hipStream_t stream) {
  const float* in   = (const float*)d_in[0];
  const float* W_fm = (const float*)d_in[1];
  const float* b_fm = (const float*)d_in[2];
  const float* W_c1 = (const float*)d_in[3];
  const float* b_c1 = (const float*)d_in[4];
  const float* W_p1 = (const float*)d_in[5];
  const float* b_p1 = (const float*)d_in[6];
  const float* W_c2 = (const float*)d_in[7];
  const float* b_c2 = (const float*)d_in[8];
  const float* W_p2 = (const float*)d_in[9];
  const float* b_p2 = (const float*)d_in[10];
  const float* W_c3 = (const float*)d_in[11];
  const float* b_c3 = (const float*)d_in[12];
  const float* rot  = (const float*)d_in[13];
  const float* ent  = (const float*)d_in[14];
  const float* conv_w = (const float*)d_in[15];
  const float* conv_b = (const float*)d_in[16];
  const float* head_w = (const float*)d_in[17];
  const float* head_b = (const float*)d_in[18];
  float* out = (float*)d_out;

  char* ws = (char*)d_ws;
  float4* qv  = (float4*)(ws + 0);            // 128 KB
  float4* kvx = (float4*)(ws + (128 << 10));  // 256 KB (k/v interleaved)
  float*  l_arr = (float*)(ws + (384 << 10));                          // 1 MB
  float4* o_arr = (float4*)(ws + (384 << 10) + NSPLIT * BATCH * 4);    // 4 MB

  mlp_kernel<<<BATCH / BLKM, BLKM, 0, stream>>>(
      in, W_fm, b_fm, W_c1, b_c1, W_p1, b_p1, W_c2, b_c2, W_p2, b_p2, W_c3,
      b_c3, rot, ent, qv, kvx);

  dim3 grid(NSPLIT, NQCHUNK);  // x = split (K$-sharing co-residency)
  attn_partial<<<grid, BLK, 0, stream>>>(kvx, qv, l_arr, o_arr);

  combine_kernel<<<BATCH / BLKC, BLKC, 0, stream>>>(
      l_arr, o_arr, conv_w, conv_b, head_w, head_b, out);
}